// Round 8
// baseline (308.710 us; speedup 1.0000x reference)
//
#include <hip/hip_runtime.h>
#include <hip/hip_bf16.h>

#define BB 2
#define S 2048
#define DM 1024
#define H 16
#define ADIM 64
#define NP 33

typedef __bf16 bf16x8 __attribute__((ext_vector_type(8)));
typedef __bf16 bf16x4 __attribute__((ext_vector_type(4)));
typedef float f32x4 __attribute__((ext_vector_type(4)));

// async global->LDS, 16B per lane (dest = wave-uniform base + lane*16)
__device__ __forceinline__ void gload16(const void* g, void* l) {
  __builtin_amdgcn_global_load_lds(
      (__attribute__((address_space(1))) void*)(g),
      (__attribute__((address_space(3))) void*)(l), 16, 0, 0);
}

// ---- fp32 -> bf16 elementwise (8 elems/thread, coalesced) ---------------
__global__ __launch_bounds__(256) void tobf16(
    const float* __restrict__ X0, const float* __restrict__ X1,
    const float* __restrict__ X2, __bf16* __restrict__ Y0,
    __bf16* __restrict__ Y1, __bf16* __restrict__ Y2) {
  const float* X; __bf16* Y;
  switch (blockIdx.z) {
    case 0: X = X0; Y = Y0; break;
    case 1: X = X1; Y = Y1; break;
    default: X = X2; Y = Y2; break;
  }
  size_t i = ((size_t)blockIdx.x * 256 + threadIdx.x) * 8;
  float4 a0 = *(const float4*)(X + i);
  float4 a1 = *(const float4*)(X + i + 4);
  bf16x8 v;
  v[0] = (__bf16)a0.x; v[1] = (__bf16)a0.y;
  v[2] = (__bf16)a0.z; v[3] = (__bf16)a0.w;
  v[4] = (__bf16)a1.x; v[5] = (__bf16)a1.y;
  v[6] = (__bf16)a1.z; v[7] = (__bf16)a1.w;
  *(bf16x8*)(Y + i) = v;
}

// ---- weight transpose: fp32 [k][n] -> bf16 [n][k], 64x64 tiles ----------
// 4-way: z selects the matrix (big-ws path folds Wo into the same dispatch)
__global__ __launch_bounds__(256) void wtrans(
    const float* __restrict__ W0, const float* __restrict__ W1,
    const float* __restrict__ W2, const float* __restrict__ W3,
    __bf16* __restrict__ T0, __bf16* __restrict__ T1,
    __bf16* __restrict__ T2, __bf16* __restrict__ T3) {
  const float* W; __bf16* T;
  switch (blockIdx.z) {
    case 0: W = W0; T = T0; break;
    case 1: W = W1; T = T1; break;
    case 2: W = W2; T = T2; break;
    default: W = W3; T = T3; break;
  }
  __shared__ __bf16 tile[64][65];
  int j = threadIdx.x & 63, i0 = threadIdx.x >> 6;
  int n0 = blockIdx.x * 64, k0 = blockIdx.y * 64;
#pragma unroll
  for (int p = 0; p < 16; ++p) {
    int i = i0 + p * 4;
    tile[i][j] = (__bf16)W[(size_t)(k0 + i) * DM + n0 + j];
  }
  __syncthreads();
#pragma unroll
  for (int p = 0; p < 16; ++p) {
    int i = i0 + p * 4;
    T[(size_t)(n0 + i) * DM + k0 + j] = tile[j][i];
  }
}

// ---- GEMM body: C = A @ BT^T  (BT = [n][k] bf16) ------------------------
#define LDK 40  // padded LDS k-stride for the reg-staged fp32-A path
template <bool A_FP32, int BN, typename CT>
__device__ __forceinline__ void gemm_body(const void* __restrict__ Av,
                                          const __bf16* __restrict__ BT,
                                          CT* __restrict__ C, int mode,
                                          int m0, int n0) {
  constexpr int NF = BN / 32;  // per-wave n fragments
  constexpr int BH = BN / 16;  // 16-row halves in B tile
  __shared__ __align__(16) __bf16 As[128 * LDK];  // bf16 path uses stride 32
  __shared__ __align__(16) __bf16 Bs[BN * 32];    // linear (gload_lds dest)
  int t = threadIdx.x;
  int w = t >> 6, lane = t & 63, l15 = lane & 15, quad = lane >> 4;
  int wm = w >> 1, wn = w & 1;
  constexpr int LA = A_FP32 ? LDK : 32;
  f32x4 acc[4][NF] = {};
  int lr = t >> 2;          // 0..63  fp32-A staging row
  int lk = (t & 3) * 8;     // 0,8,16,24
  int r4 = lane >> 2;       // 0..15  gload row within 16-row half
  int c8 = (lane & 3) * 8;  // 0,8,16,24
  for (int k0 = 0; k0 < DM; k0 += 32) {
    if constexpr (A_FP32) {
#pragma unroll
      for (int rr = 0; rr < 2; ++rr) {
        int row = rr * 64 + lr;
        const float* src = (const float*)Av + (size_t)(m0 + row) * DM + k0 + lk;
        float4 a0 = *(const float4*)src;
        float4 a1 = *(const float4*)(src + 4);
        bf16x8 v;
        v[0] = (__bf16)a0.x; v[1] = (__bf16)a0.y;
        v[2] = (__bf16)a0.z; v[3] = (__bf16)a0.w;
        v[4] = (__bf16)a1.x; v[5] = (__bf16)a1.y;
        v[6] = (__bf16)a1.z; v[7] = (__bf16)a1.w;
        *(bf16x8*)&As[row * LDK + lk] = v;
      }
    } else {
#pragma unroll
      for (int q = 0; q < 2; ++q) {
        int half = w * 2 + q;  // 0..7 -> 16-row band
        gload16((const __bf16*)Av + (size_t)(m0 + half * 16 + r4) * DM + k0 + c8,
                &As[half * 512]);
      }
    }
#pragma unroll
    for (int q = 0; q < BH / 4; ++q) {
      int half = w * (BH / 4) + q;
      gload16(&BT[(size_t)(n0 + half * 16 + r4) * DM + k0 + c8],
              &Bs[half * 512]);
    }
    __syncthreads();
    bf16x8 af[4], bfr[NF];
#pragma unroll
    for (int mi = 0; mi < 4; ++mi)
      af[mi] = *(const bf16x8*)&As[(wm * 64 + mi * 16 + l15) * LA + quad * 8];
#pragma unroll
    for (int ni = 0; ni < NF; ++ni)
      bfr[ni] =
          *(const bf16x8*)&Bs[(wn * (BN / 2) + ni * 16 + l15) * 32 + quad * 8];
#pragma unroll
    for (int mi = 0; mi < 4; ++mi)
#pragma unroll
      for (int ni = 0; ni < NF; ++ni)
        acc[mi][ni] = __builtin_amdgcn_mfma_f32_16x16x32_bf16(
            af[mi], bfr[ni], acc[mi][ni], 0, 0, 0);
    __syncthreads();
  }
#pragma unroll
  for (int mi = 0; mi < 4; ++mi)
#pragma unroll
    for (int ni = 0; ni < NF; ++ni)
#pragma unroll
      for (int r = 0; r < 4; ++r) {
        int row = m0 + wm * 64 + mi * 16 + quad * 4 + r;
        int col = n0 + wn * (BN / 2) + ni * 16 + l15;
        CT v = (CT)acc[mi][ni][r];
        if (mode == 0) {
          C[(size_t)row * DM + col] = v;
        } else if (mode == 3) {
          int hh = row >> 6, dd = row & (ADIM - 1);
          int bb = col >> 11, ss = col & (S - 1);
          C[((size_t)(bb * H + hh) * ADIM + dd) * S + ss] = v;
        } else {
          int b = row >> 11, s = row & (S - 1);
          int h = col >> 6, d = col & (ADIM - 1);
          if (mode == 1)
            C[((size_t)(b * H + h) * S + s) * ADIM + d] = v;
          else
            C[((size_t)(b * H + h) * ADIM + d) * S + s] = v;
        }
      }
}

// fused Q/K/V projection, fp32-A fallback path (small-ws only)
__global__ __launch_bounds__(256) void proj3(
    const float* __restrict__ iQ, const float* __restrict__ iK,
    const float* __restrict__ iV, const __bf16* __restrict__ WqT,
    const __bf16* __restrict__ WkT, const __bf16* __restrict__ WvT,
    __bf16* __restrict__ Qw, __bf16* __restrict__ Kw,
    __bf16* __restrict__ Vt) {
  const float* A; const __bf16* B; __bf16* C; int mode;
  switch (blockIdx.z) {
    case 0: A = iQ; B = WqT; C = Qw; mode = 1; break;
    case 1: A = iK; B = WkT; C = Kw; mode = 1; break;
    default: A = iV; B = WvT; C = Vt; mode = 2; break;
  }
  int i2 = blockIdx.x + (blockIdx.y << 3);
  int xcd = i2 & 7, slot = i2 >> 3;
  int m0 = (xcd + ((slot >> 3) << 3)) * 128;
  int n0 = (slot & 7) * 128;
  gemm_body<true, 128, __bf16>(A, B, C, mode, m0, n0);
}

// fused Q/K/V projection, bf16 path, ONE dispatch (768 blocks):
// z=0,1: Q/K standard (mode 1); z=2: V as transposed GEMM (A=WvT, B=iVb),
// mode-3 epilogue -> s-contiguous coalesced Vt stores.
__global__ __launch_bounds__(256) void proj3b(
    const __bf16* __restrict__ Qb, const __bf16* __restrict__ Kb,
    const __bf16* __restrict__ Vb, const __bf16* __restrict__ WqT,
    const __bf16* __restrict__ WkT, const __bf16* __restrict__ WvT,
    __bf16* __restrict__ Qw, __bf16* __restrict__ Kw,
    __bf16* __restrict__ Vt) {
  int i2 = blockIdx.x + (blockIdx.y << 3);
  if (blockIdx.z == 2) {
    int m0 = (i2 & 7) * 128;   // d-tile (8)
    int n0 = (i2 >> 3) * 128;  // b*S+s tile (32)
    gemm_body<false, 128, __bf16>(WvT, Vb, Vt, 3, m0, n0);
  } else {
    const __bf16* A; const __bf16* B; __bf16* C;
    if (blockIdx.z == 0) { A = Qb; B = WqT; C = Qw; }
    else                 { A = Kb; B = WkT; C = Kw; }
    int xcd = i2 & 7, slot = i2 >> 3;
    int m0 = (xcd + ((slot >> 3) << 3)) * 128;
    int n0 = (slot & 7) * 128;
    gemm_body<false, 128, __bf16>(A, B, C, 1, m0, n0);
  }
}

__global__ __launch_bounds__(256) void gemm_final(
    const __bf16* __restrict__ ctx, const __bf16* __restrict__ WoT,
    float* __restrict__ out) {
  // 128x64 tile -> 512 blocks -> 2 blocks/CU
  int i2 = blockIdx.x + (blockIdx.y << 4);
  int xcd = i2 & 7, slot = i2 >> 3;  // slot 0..63
  int m0 = ((xcd << 2) + (slot >> 4)) * 128;
  int n0 = (slot & 15) * 64;
  gemm_body<false, 64, float>(ctx, WoT, out, 0, m0, n0);
}

// ---- flash attention, round 8: r7 structure (swapped-QK, XOR swizzle,
// packed-b64 P) MINUS the V LDS staging: V^T fragments load directly
// global->reg in MFMA B-layout (Vt is [d][s] for exactly this). Issued at
// loop top, consumed after staging-barrier + QK + softmax (~400cy window);
// L2-local via the head-partitioned XCD swizzle. LDS-pipe cycles ~-40%.
#define SWZ(row, sl) (((row) << 6) + ((((sl) ^ ((row) & 7))) << 3))
__global__ __launch_bounds__(256) void attn_flash(
    const __bf16* __restrict__ Qw, const __bf16* __restrict__ Kw,
    const __bf16* __restrict__ Vt, const float* __restrict__ pemb,
    __bf16* __restrict__ ctx) {
  // head-partitioned XCD swizzle (r6, FETCH -5.6x): XCD a gets heads
  // 4a..4a+3 x all 32 q-blocks (2MB K/V working set per XCD L2).
  int i = blockIdx.x + (blockIdx.y << 5);
  int a = i & 7, j = i >> 3;
  int bh = (a << 2) + (j >> 5);
  int q0 = (j & 31) * 64;
  int b = bh >> 4, h = bh & 15;
  int t = threadIdx.x, w = t >> 6, lane = t & 63, l15 = lane & 15,
      quad = lane >> 4;
  const __bf16* Qh = Qw + (size_t)bh * S * ADIM;
  const __bf16* Kh = Kw + (size_t)bh * S * ADIM;
  const __bf16* Vh = Vt + (size_t)bh * ADIM * S;  // [d][s]

  // LDS: Ks [64][64] 8192 | pband [64][34] f32 8704 | pbuf 4x2048 = 25088
  __shared__ __align__(16) char smem[25088];
  __bf16* Ks = (__bf16*)smem;
  float* pband = (float*)(smem + 8192);
  __bf16* pbufw = (__bf16*)(smem + 16896 + w * 2048);  // [16][64] per wave
  __bf16* peb = (__bf16*)smem;  // overlay [48][64] 6144B: dead pre-staging

  for (int ii = t; ii < 48 * 64; ii += 256) {
    int r = ii >> 6, d = ii & 63;
    peb[r * 64 + d] = (r < NP) ? (__bf16)pemb[ii] : (__bf16)0.f;
  }

  int qa = q0 + w * 16 + l15;
  bf16x8 qf0 = *(const bf16x8*)&Qh[(size_t)qa * ADIM + quad * 8];
  bf16x8 qf1 = *(const bf16x8*)&Qh[(size_t)qa * ADIM + 32 + quad * 8];
  __syncthreads();

  // bias band via MFMA: pband[qlocal][i0] = Q[q] . pemb[i0]
  {
    f32x4 pc[3] = {};
#pragma unroll
    for (int ni = 0; ni < 3; ++ni) {
      bf16x8 b0 = *(const bf16x8*)&peb[(ni * 16 + l15) * 64 + quad * 8];
      bf16x8 b1 = *(const bf16x8*)&peb[(ni * 16 + l15) * 64 + 32 + quad * 8];
      pc[ni] = __builtin_amdgcn_mfma_f32_16x16x32_bf16(qf0, b0, pc[ni], 0, 0, 0);
      pc[ni] = __builtin_amdgcn_mfma_f32_16x16x32_bf16(qf1, b1, pc[ni], 0, 0, 0);
    }
#pragma unroll
    for (int ni = 0; ni < 3; ++ni)
#pragma unroll
      for (int r = 0; r < 4; ++r) {
        int col = ni * 16 + l15;
        if (col < NP) pband[(w * 16 + quad * 4 + r) * 34 + col] = pc[ni][r];
      }
  }
  __syncthreads();  // pband ready; peb region free for Ks

  int qg = q0 + w * 16 + l15;       // this lane's q row (swapped layout)
  int qc = q0 + w * 16 + quad * 4;  // PV C-layout base q row
  int qw0 = q0 + w * 16;            // wave's first q row (wave-uniform)
  const float* pbrow = pband + (w * 16 + l15) * 34;  // this lane's bias row
  float lsum = 0.f;
  f32x4 o[4] = {};

  // saturated-edge biases: per-lane SCALARS (q is lane-constant)
  float pb0s = pbrow[0] * 0.125f;
  float pb32s = pbrow[32] * 0.125f;

  // cooperative K staging: thread t covers rows srow, srow+32, slot sslot
  int srow = t >> 3;   // 0..31
  int sslot = t & 7;   // 16B slot index
  int scol = sslot * 8;
  bf16x8 k0r = *(const bf16x8*)&Kh[(size_t)srow * ADIM + scol];
  bf16x8 k1r = *(const bf16x8*)&Kh[(size_t)(32 + srow) * ADIM + scol];

  for (int s0 = 0; s0 < S; s0 += 64) {
    // V^T fragments for THIS tile: global->reg, MFMA B-layout, issued
    // early so HBM/L2 latency hides under staging + QK + softmax
    bf16x8 vb0[4], vb1[4];
#pragma unroll
    for (int nt = 0; nt < 4; ++nt) {
      int vrow = nt * 16 + l15;
      vb0[nt] = *(const bf16x8*)&Vh[(size_t)vrow * S + s0 + quad * 8];
      vb1[nt] = *(const bf16x8*)&Vh[(size_t)vrow * S + s0 + 32 + quad * 8];
    }
    __syncthreads();  // previous tile's compute done -> safe to overwrite
    *(bf16x8*)&Ks[SWZ(srow, sslot)] = k0r;
    *(bf16x8*)&Ks[SWZ(32 + srow, sslot)] = k1r;
    int sn = s0 + 64;
    if (sn < S) {  // issue next tile's K loads
      k0r = *(const bf16x8*)&Kh[(size_t)(sn + srow) * ADIM + scol];
      k1r = *(const bf16x8*)&Kh[(size_t)(sn + 32 + srow) * ADIM + scol];
    }
    __syncthreads();  // staged tile visible

    // QK swapped: c[jj] = mfma(K, Q) -> C[s][q]; lane holds q = l15,
    // s = s0 + jj*16 + quad*4 + r
    f32x4 c[4];
#pragma unroll
    for (int jj = 0; jj < 4; ++jj) {
      f32x4 cj = {};
      int krow = jj * 16 + l15;
      bf16x8 kb0 = *(const bf16x8*)&Ks[SWZ(krow, quad)];
      bf16x8 kb1 = *(const bf16x8*)&Ks[SWZ(krow, 4 + quad)];
      cj = __builtin_amdgcn_mfma_f32_16x16x32_bf16(kb0, qf0, cj, 0, 0, 0);
      cj = __builtin_amdgcn_mfma_f32_16x16x32_bf16(kb1, qf1, cj, 0, 0, 0);
      c[jj] = cj;
    }

    // softmax numerators; lsum is a per-lane scalar (one q per lane)
    float pv[4][4];
    bool below = (s0 + 79 <= qw0);  // whole tile saturates low
    bool above = (s0 >= qw0 + 31);  // whole tile saturates high
    if (below || above) {
      float pb = below ? pb0s : pb32s;
#pragma unroll
      for (int jj = 0; jj < 4; ++jj)
#pragma unroll
        for (int r = 0; r < 4; ++r) {
          float e = __expf(__builtin_fmaf(c[jj][r], 0.125f, pb));
          lsum += e;
          pv[jj][r] = e;
        }
    } else {
#pragma unroll
      for (int jj = 0; jj < 4; ++jj)
#pragma unroll
        for (int r = 0; r < 4; ++r) {
          int sg = s0 + jj * 16 + quad * 4 + r;
          int i0 = sg - qg; i0 = i0 < -16 ? -16 : (i0 > 16 ? 16 : i0); i0 += 16;
          float e = __expf((c[jj][r] + pbrow[i0]) * 0.125f);
          lsum += e;
          pv[jj][r] = e;
        }
    }

    // packed P round-trip: 4x ds_write_b64 (bank-even swizzle), 2x b128 read
#pragma unroll
    for (int jj = 0; jj < 4; ++jj) {
      bf16x4 pw;
      pw[0] = (__bf16)pv[jj][0]; pw[1] = (__bf16)pv[jj][1];
      pw[2] = (__bf16)pv[jj][2]; pw[3] = (__bf16)pv[jj][3];
      int sl = (2 * jj + (quad >> 1)) ^ (l15 & 7);
      *(bf16x4*)&pbufw[(l15 << 6) + (sl << 3) + (quad & 1) * 4] = pw;
    }
    bf16x8 pa0 = *(const bf16x8*)&pbufw[SWZ(l15, quad)];
    bf16x8 pa1 = *(const bf16x8*)&pbufw[SWZ(l15, 4 + quad)];

    // PV: o[nt] += P(16q x 64s) @ V^T fragments (V in registers)
#pragma unroll
    for (int nt = 0; nt < 4; ++nt) {
      o[nt] = __builtin_amdgcn_mfma_f32_16x16x32_bf16(pa0, vb0[nt], o[nt], 0, 0, 0);
      o[nt] = __builtin_amdgcn_mfma_f32_16x16x32_bf16(pa1, vb1[nt], o[nt], 0, 0, 0);
    }
  }

  // epilogue: lsum reduce across the 4 quads holding the same q, then
  // redistribute to the PV C-layout (q = quad*4 + r)
  lsum += __shfl_xor(lsum, 16, 64);
  lsum += __shfl_xor(lsum, 32, 64);
  float ls[4];
#pragma unroll
  for (int r = 0; r < 4; ++r) ls[r] = __shfl(lsum, quad * 4 + r, 64);
#pragma unroll
  for (int nt = 0; nt < 4; ++nt)
#pragma unroll
    for (int r = 0; r < 4; ++r) {
      int qq = qc + r;
      int d = nt * 16 + l15;
      ctx[(size_t)(b * S + qq) * DM + h * ADIM + d] =
          (__bf16)(o[nt][r] / ls[r]);
    }
}

extern "C" void kernel_launch(void* const* d_in, const int* in_sizes, int n_in,
                              void* d_out, int out_size, void* d_ws,
                              size_t ws_size, hipStream_t stream) {
  bool sizes_ok =
      (n_in == 8 && in_sizes[0] == BB * S * DM && in_sizes[1] == BB * S * DM &&
       in_sizes[2] == BB * S * DM && in_sizes[3] == DM * DM &&
       in_sizes[4] == DM * DM && in_sizes[5] == DM * DM &&
       in_sizes[6] == DM * DM && in_sizes[7] == NP * ADIM &&
       out_size == BB * S * DM);
  if (!sizes_ok) return;
  if (ws_size < 33ull * 1024 * 1024) return;

  const float* iQ = (const float*)d_in[0];
  const float* iK = (const float*)d_in[1];
  const float* iV = (const float*)d_in[2];
  const float* Wq = (const float*)d_in[3];
  const float* Wk = (const float*)d_in[4];
  const float* Wv = (const float*)d_in[5];
  const float* Wo = (const float*)d_in[6];
  const float* pemb = (const float*)d_in[7];

  char* w = (char*)d_ws;
  const size_t MB = 1024 * 1024;
  __bf16* Qw  = (__bf16*)(w + 0 * MB);
  __bf16* Kw  = (__bf16*)(w + 8 * MB);
  __bf16* Vt  = (__bf16*)(w + 16 * MB);  // [b,h,d,s]
  __bf16* ctx = (__bf16*)(w + 24 * MB);  // written by attn (24..32)
  __bf16* WqT = (__bf16*)(w + 24 * MB);  // overlay: dead before attn
  __bf16* WkT = (__bf16*)(w + 26 * MB);
  __bf16* WvT = (__bf16*)(w + 28 * MB);

  bool big = ws_size >= 58ull * 1024 * 1024;     // WoT @56MB, merged wtrans
  bool mid = ws_size >= 56ull * 1024 * 1024;     // bf16 prepass path
  __bf16* WoT = big ? (__bf16*)(w + 56 * MB) : (__bf16*)(w + 0 * MB);

  if (mid) {
    __bf16* Qb = (__bf16*)(w + 32 * MB);
    __bf16* Kb = (__bf16*)(w + 40 * MB);
    __bf16* Vb = (__bf16*)(w + 48 * MB);
    // transpose all 4 weights in one dispatch when WoT has a safe home
    wtrans<<<dim3(16, 16, big ? 4 : 3), 256, 0, stream>>>(
        Wq, Wk, Wv, Wo, WqT, WkT, WvT, WoT);
    tobf16<<<dim3(2048, 1, 3), 256, 0, stream>>>(iQ, iK, iV, Qb, Kb, Vb);
    proj3b<<<dim3(8, 32, 3), 256, 0, stream>>>(Qb, Kb, Vb, WqT, WkT, WvT,
                                               Qw, Kw, Vt);
    attn_flash<<<dim3(S / 64, BB * H), 256, 0, stream>>>(Qw, Kw, Vt, pemb,
                                                         ctx);
    if (!big)  // Qw slot only frees up after attn
      wtrans<<<dim3(16, 16, 1), 256, 0, stream>>>(Wo, Wo, Wo, Wo,
                                                  WoT, WoT, WoT, WoT);
  } else {
    wtrans<<<dim3(16, 16, 3), 256, 0, stream>>>(Wq, Wk, Wv, Wq,
                                                WqT, WkT, WvT, WqT);
    proj3<<<dim3(8, 32, 3), 256, 0, stream>>>(iQ, iK, iV, WqT, WkT, WvT,
                                              Qw, Kw, Vt);
    attn_flash<<<dim3(S / 64, BB * H), 256, 0, stream>>>(Qw, Kw, Vt, pemb,
                                                         ctx);
    wtrans<<<dim3(16, 16, 1), 256, 0, stream>>>(Wo, Wo, Wo, Wo,
                                                WoT, WoT, WoT, WoT);
  }
  gemm_final<<<dim3(16, 32), 256, 0, stream>>>(ctx, WoT, (float*)d_out);
}

// Round 10
// 232.878 us; speedup vs baseline: 1.3256x; 1.3256x over previous
//
#include <hip/hip_runtime.h>
#include <hip/hip_bf16.h>

#define BB 2
#define S 2048
#define DM 1024
#define H 16
#define ADIM 64
#define NP 33

typedef __bf16 bf16x8 __attribute__((ext_vector_type(8)));
typedef __bf16 bf16x4 __attribute__((ext_vector_type(4)));
typedef float f32x4 __attribute__((ext_vector_type(4)));

// async global->LDS, 16B per lane (dest = wave-uniform base + lane*16)
__device__ __forceinline__ void gload16(const void* g, void* l) {
  __builtin_amdgcn_global_load_lds(
      (__attribute__((address_space(1))) void*)(g),
      (__attribute__((address_space(3))) void*)(l), 16, 0, 0);
}

// ---- fp32 -> bf16 elementwise (8 elems/thread, coalesced) ---------------
__global__ __launch_bounds__(256) void tobf16(
    const float* __restrict__ X0, const float* __restrict__ X1,
    const float* __restrict__ X2, __bf16* __restrict__ Y0,
    __bf16* __restrict__ Y1, __bf16* __restrict__ Y2) {
  const float* X; __bf16* Y;
  switch (blockIdx.z) {
    case 0: X = X0; Y = Y0; break;
    case 1: X = X1; Y = Y1; break;
    default: X = X2; Y = Y2; break;
  }
  size_t i = ((size_t)blockIdx.x * 256 + threadIdx.x) * 8;
  float4 a0 = *(const float4*)(X + i);
  float4 a1 = *(const float4*)(X + i + 4);
  bf16x8 v;
  v[0] = (__bf16)a0.x; v[1] = (__bf16)a0.y;
  v[2] = (__bf16)a0.z; v[3] = (__bf16)a0.w;
  v[4] = (__bf16)a1.x; v[5] = (__bf16)a1.y;
  v[6] = (__bf16)a1.z; v[7] = (__bf16)a1.w;
  *(bf16x8*)(Y + i) = v;
}

// ---- weight transpose: fp32 [k][n] -> bf16 [n][k], 64x64 tiles ----------
// 4-way: z selects the matrix (big-ws path folds Wo into the same dispatch)
__global__ __launch_bounds__(256) void wtrans(
    const float* __restrict__ W0, const float* __restrict__ W1,
    const float* __restrict__ W2, const float* __restrict__ W3,
    __bf16* __restrict__ T0, __bf16* __restrict__ T1,
    __bf16* __restrict__ T2, __bf16* __restrict__ T3) {
  const float* W; __bf16* T;
  switch (blockIdx.z) {
    case 0: W = W0; T = T0; break;
    case 1: W = W1; T = T1; break;
    case 2: W = W2; T = T2; break;
    default: W = W3; T = T3; break;
  }
  __shared__ __bf16 tile[64][65];
  int j = threadIdx.x & 63, i0 = threadIdx.x >> 6;
  int n0 = blockIdx.x * 64, k0 = blockIdx.y * 64;
#pragma unroll
  for (int p = 0; p < 16; ++p) {
    int i = i0 + p * 4;
    tile[i][j] = (__bf16)W[(size_t)(k0 + i) * DM + n0 + j];
  }
  __syncthreads();
#pragma unroll
  for (int p = 0; p < 16; ++p) {
    int i = i0 + p * 4;
    T[(size_t)(n0 + i) * DM + k0 + j] = tile[j][i];
  }
}

// ---- GEMM body: C = A @ BT^T  (BT = [n][k] bf16) ------------------------
#define LDK 40  // padded LDS k-stride for the reg-staged fp32-A path
template <bool A_FP32, int BN, typename CT>
__device__ __forceinline__ void gemm_body(const void* __restrict__ Av,
                                          const __bf16* __restrict__ BT,
                                          CT* __restrict__ C, int mode,
                                          int m0, int n0) {
  constexpr int NF = BN / 32;  // per-wave n fragments
  constexpr int BH = BN / 16;  // 16-row halves in B tile
  __shared__ __align__(16) __bf16 As[128 * LDK];  // bf16 path uses stride 32
  __shared__ __align__(16) __bf16 Bs[BN * 32];    // linear (gload_lds dest)
  int t = threadIdx.x;
  int w = t >> 6, lane = t & 63, l15 = lane & 15, quad = lane >> 4;
  int wm = w >> 1, wn = w & 1;
  constexpr int LA = A_FP32 ? LDK : 32;
  f32x4 acc[4][NF] = {};
  int lr = t >> 2;          // 0..63  fp32-A staging row
  int lk = (t & 3) * 8;     // 0,8,16,24
  int r4 = lane >> 2;       // 0..15  gload row within 16-row half
  int c8 = (lane & 3) * 8;  // 0,8,16,24
  for (int k0 = 0; k0 < DM; k0 += 32) {
    if constexpr (A_FP32) {
#pragma unroll
      for (int rr = 0; rr < 2; ++rr) {
        int row = rr * 64 + lr;
        const float* src = (const float*)Av + (size_t)(m0 + row) * DM + k0 + lk;
        float4 a0 = *(const float4*)src;
        float4 a1 = *(const float4*)(src + 4);
        bf16x8 v;
        v[0] = (__bf16)a0.x; v[1] = (__bf16)a0.y;
        v[2] = (__bf16)a0.z; v[3] = (__bf16)a0.w;
        v[4] = (__bf16)a1.x; v[5] = (__bf16)a1.y;
        v[6] = (__bf16)a1.z; v[7] = (__bf16)a1.w;
        *(bf16x8*)&As[row * LDK + lk] = v;
      }
    } else {
#pragma unroll
      for (int q = 0; q < 2; ++q) {
        int half = w * 2 + q;  // 0..7 -> 16-row band
        gload16((const __bf16*)Av + (size_t)(m0 + half * 16 + r4) * DM + k0 + c8,
                &As[half * 512]);
      }
    }
#pragma unroll
    for (int q = 0; q < BH / 4; ++q) {
      int half = w * (BH / 4) + q;
      gload16(&BT[(size_t)(n0 + half * 16 + r4) * DM + k0 + c8],
              &Bs[half * 512]);
    }
    __syncthreads();
    bf16x8 af[4], bfr[NF];
#pragma unroll
    for (int mi = 0; mi < 4; ++mi)
      af[mi] = *(const bf16x8*)&As[(wm * 64 + mi * 16 + l15) * LA + quad * 8];
#pragma unroll
    for (int ni = 0; ni < NF; ++ni)
      bfr[ni] =
          *(const bf16x8*)&Bs[(wn * (BN / 2) + ni * 16 + l15) * 32 + quad * 8];
#pragma unroll
    for (int mi = 0; mi < 4; ++mi)
#pragma unroll
      for (int ni = 0; ni < NF; ++ni)
        acc[mi][ni] = __builtin_amdgcn_mfma_f32_16x16x32_bf16(
            af[mi], bfr[ni], acc[mi][ni], 0, 0, 0);
    __syncthreads();
  }
#pragma unroll
  for (int mi = 0; mi < 4; ++mi)
#pragma unroll
    for (int ni = 0; ni < NF; ++ni)
#pragma unroll
      for (int r = 0; r < 4; ++r) {
        int row = m0 + wm * 64 + mi * 16 + quad * 4 + r;
        int col = n0 + wn * (BN / 2) + ni * 16 + l15;
        CT v = (CT)acc[mi][ni][r];
        if (mode == 0) {
          C[(size_t)row * DM + col] = v;
        } else if (mode == 3) {
          int hh = row >> 6, dd = row & (ADIM - 1);
          int bb = col >> 11, ss = col & (S - 1);
          C[((size_t)(bb * H + hh) * ADIM + dd) * S + ss] = v;
        } else {
          int b = row >> 11, s = row & (S - 1);
          int h = col >> 6, d = col & (ADIM - 1);
          if (mode == 1)
            C[((size_t)(b * H + h) * S + s) * ADIM + d] = v;
          else
            C[((size_t)(b * H + h) * ADIM + d) * S + s] = v;
        }
      }
}

// fused Q/K/V projection, fp32-A fallback path (small-ws only)
__global__ __launch_bounds__(256) void proj3(
    const float* __restrict__ iQ, const float* __restrict__ iK,
    const float* __restrict__ iV, const __bf16* __restrict__ WqT,
    const __bf16* __restrict__ WkT, const __bf16* __restrict__ WvT,
    __bf16* __restrict__ Qw, __bf16* __restrict__ Kw,
    __bf16* __restrict__ Vt) {
  const float* A; const __bf16* B; __bf16* C; int mode;
  switch (blockIdx.z) {
    case 0: A = iQ; B = WqT; C = Qw; mode = 1; break;
    case 1: A = iK; B = WkT; C = Kw; mode = 1; break;
    default: A = iV; B = WvT; C = Vt; mode = 2; break;
  }
  int i2 = blockIdx.x + (blockIdx.y << 3);
  int xcd = i2 & 7, slot = i2 >> 3;
  int m0 = (xcd + ((slot >> 3) << 3)) * 128;
  int n0 = (slot & 7) * 128;
  gemm_body<true, 128, __bf16>(A, B, C, mode, m0, n0);
}

// fused Q/K/V projection, bf16 path, ONE dispatch (768 blocks):
// z=0,1: Q/K standard (mode 1); z=2: V as transposed GEMM (A=WvT, B=iVb),
// mode-3 epilogue -> s-contiguous coalesced Vt stores.
__global__ __launch_bounds__(256) void proj3b(
    const __bf16* __restrict__ Qb, const __bf16* __restrict__ Kb,
    const __bf16* __restrict__ Vb, const __bf16* __restrict__ WqT,
    const __bf16* __restrict__ WkT, const __bf16* __restrict__ WvT,
    __bf16* __restrict__ Qw, __bf16* __restrict__ Kw,
    __bf16* __restrict__ Vt) {
  int i2 = blockIdx.x + (blockIdx.y << 3);
  if (blockIdx.z == 2) {
    int m0 = (i2 & 7) * 128;   // d-tile (8)
    int n0 = (i2 >> 3) * 128;  // b*S+s tile (32)
    gemm_body<false, 128, __bf16>(WvT, Vb, Vt, 3, m0, n0);
  } else {
    const __bf16* A; const __bf16* B; __bf16* C;
    if (blockIdx.z == 0) { A = Qb; B = WqT; C = Qw; }
    else                 { A = Kb; B = WkT; C = Kw; }
    int xcd = i2 & 7, slot = i2 >> 3;
    int m0 = (xcd + ((slot >> 3) << 3)) * 128;
    int n0 = (slot & 7) * 128;
    gemm_body<false, 128, __bf16>(A, B, C, 1, m0, n0);
  }
}

__global__ __launch_bounds__(256) void gemm_final(
    const __bf16* __restrict__ ctx, const __bf16* __restrict__ WoT,
    float* __restrict__ out) {
  // 128x64 tile -> 512 blocks -> 2 blocks/CU
  int i2 = blockIdx.x + (blockIdx.y << 4);
  int xcd = i2 & 7, slot = i2 >> 3;  // slot 0..63
  int m0 = ((xcd << 2) + (slot >> 4)) * 128;
  int n0 = (slot & 15) * 64;
  gemm_body<false, 64, float>(ctx, WoT, out, 0, m0, n0);
}

// ---- flash attention: ROUND-7 structure verbatim (best measured, 80.3us):
// swapped-QK (q = lane&15 lane-constant), bank-even XOR swizzle on all LDS
// tiles, packed-b64 P round-trip, K AND V staged through LDS (twice-proven:
// direct global fragment loads are 16-segment strided -> issue-bound
// collapse, r2 & r8). Head-partitioned XCD swizzle (FETCH -5.6x).
#define SWZ(row, sl) (((row) << 6) + ((((sl) ^ ((row) & 7))) << 3))
__global__ __launch_bounds__(256) void attn_flash(
    const __bf16* __restrict__ Qw, const __bf16* __restrict__ Kw,
    const __bf16* __restrict__ Vt, const float* __restrict__ pemb,
    __bf16* __restrict__ ctx) {
  // XCD a gets heads 4a..4a+3 x all 32 q-blocks (2MB K/V set per XCD L2)
  int i = blockIdx.x + (blockIdx.y << 5);
  int a = i & 7, j = i >> 3;
  int bh = (a << 2) + (j >> 5);
  int q0 = (j & 31) * 64;
  int b = bh >> 4, h = bh & 15;
  int t = threadIdx.x, w = t >> 6, lane = t & 63, l15 = lane & 15,
      quad = lane >> 4;
  const __bf16* Qh = Qw + (size_t)bh * S * ADIM;
  const __bf16* Kh = Kw + (size_t)bh * S * ADIM;
  const __bf16* Vh = Vt + (size_t)bh * ADIM * S;  // [d][s]

  // LDS: Ks [64][64] 8192 | Vs 8192 | pband [64][34] f32 8704 | pbuf 4x2048
  __shared__ __align__(16) char smem[33280];
  __bf16* Ks = (__bf16*)smem;
  __bf16* Vs = (__bf16*)(smem + 8192);
  float* pband = (float*)(smem + 16384);
  __bf16* pbufw = (__bf16*)(smem + 25088 + w * 2048);  // [16][64] per wave
  __bf16* peb = (__bf16*)smem;  // overlay [48][64]: dead before staging

  for (int ii = t; ii < 48 * 64; ii += 256) {
    int r = ii >> 6, d = ii & 63;
    peb[r * 64 + d] = (r < NP) ? (__bf16)pemb[ii] : (__bf16)0.f;
  }

  int qa = q0 + w * 16 + l15;
  bf16x8 qf0 = *(const bf16x8*)&Qh[(size_t)qa * ADIM + quad * 8];
  bf16x8 qf1 = *(const bf16x8*)&Qh[(size_t)qa * ADIM + 32 + quad * 8];
  __syncthreads();

  // bias band via MFMA: pband[qlocal][i0] = Q[q] . pemb[i0]
  {
    f32x4 pc[3] = {};
#pragma unroll
    for (int ni = 0; ni < 3; ++ni) {
      bf16x8 b0 = *(const bf16x8*)&peb[(ni * 16 + l15) * 64 + quad * 8];
      bf16x8 b1 = *(const bf16x8*)&peb[(ni * 16 + l15) * 64 + 32 + quad * 8];
      pc[ni] = __builtin_amdgcn_mfma_f32_16x16x32_bf16(qf0, b0, pc[ni], 0, 0, 0);
      pc[ni] = __builtin_amdgcn_mfma_f32_16x16x32_bf16(qf1, b1, pc[ni], 0, 0, 0);
    }
#pragma unroll
    for (int ni = 0; ni < 3; ++ni)
#pragma unroll
      for (int r = 0; r < 4; ++r) {
        int col = ni * 16 + l15;
        if (col < NP) pband[(w * 16 + quad * 4 + r) * 34 + col] = pc[ni][r];
      }
  }
  __syncthreads();  // pband ready; peb region free for Ks

  int qg = q0 + w * 16 + l15;       // this lane's q row (swapped layout)
  int qc = q0 + w * 16 + quad * 4;  // PV C-layout base q row
  int qw0 = q0 + w * 16;            // wave's first q row (wave-uniform)
  const float* pbrow = pband + (w * 16 + l15) * 34;  // this lane's bias row
  float lsum = 0.f;
  f32x4 o[4] = {};

  // saturated-edge biases: per-lane SCALARS (q is lane-constant)
  float pb0s = pbrow[0] * 0.125f;
  float pb32s = pbrow[32] * 0.125f;

  // cooperative staging: thread t covers rows srow, srow+32, slot sslot
  int srow = t >> 3;   // 0..31
  int sslot = t & 7;   // 16B slot index
  int scol = sslot * 8;
  bf16x8 k0r = *(const bf16x8*)&Kh[(size_t)srow * ADIM + scol];
  bf16x8 k1r = *(const bf16x8*)&Kh[(size_t)(32 + srow) * ADIM + scol];
  bf16x8 v0r = *(const bf16x8*)&Vh[(size_t)srow * S + scol];
  bf16x8 v1r = *(const bf16x8*)&Vh[(size_t)(32 + srow) * S + scol];

  for (int s0 = 0; s0 < S; s0 += 64) {
    __syncthreads();  // previous tile's compute done -> safe to overwrite
    *(bf16x8*)&Ks[SWZ(srow, sslot)] = k0r;
    *(bf16x8*)&Ks[SWZ(32 + srow, sslot)] = k1r;
    *(bf16x8*)&Vs[SWZ(srow, sslot)] = v0r;
    *(bf16x8*)&Vs[SWZ(32 + srow, sslot)] = v1r;
    int sn = s0 + 64;
    if (sn < S) {  // issue next tile's loads
      k0r = *(const bf16x8*)&Kh[(size_t)(sn + srow) * ADIM + scol];
      k1r = *(const bf16x8*)&Kh[(size_t)(sn + 32 + srow) * ADIM + scol];
      v0r = *(const bf16x8*)&Vh[(size_t)srow * S + sn + scol];
      v1r = *(const bf16x8*)&Vh[(size_t)(32 + srow) * S + sn + scol];
    }
    __syncthreads();  // staged tile visible

    // QK swapped: c[jj] = mfma(K, Q) -> C[s][q]; lane holds q = l15,
    // s = s0 + jj*16 + quad*4 + r
    f32x4 c[4];
#pragma unroll
    for (int jj = 0; jj < 4; ++jj) {
      f32x4 cj = {};
      int krow = jj * 16 + l15;
      bf16x8 kb0 = *(const bf16x8*)&Ks[SWZ(krow, quad)];
      bf16x8 kb1 = *(const bf16x8*)&Ks[SWZ(krow, 4 + quad)];
      cj = __builtin_amdgcn_mfma_f32_16x16x32_bf16(kb0, qf0, cj, 0, 0, 0);
      cj = __builtin_amdgcn_mfma_f32_16x16x32_bf16(kb1, qf1, cj, 0, 0, 0);
      c[jj] = cj;
    }

    // softmax numerators; lsum is a per-lane scalar (one q per lane)
    float pv[4][4];
    bool below = (s0 + 79 <= qw0);  // whole tile saturates low
    bool above = (s0 >= qw0 + 31);  // whole tile saturates high
    if (below || above) {
      float pb = below ? pb0s : pb32s;
#pragma unroll
      for (int jj = 0; jj < 4; ++jj)
#pragma unroll
        for (int r = 0; r < 4; ++r) {
          float e = __expf(__builtin_fmaf(c[jj][r], 0.125f, pb));
          lsum += e;
          pv[jj][r] = e;
        }
    } else {
#pragma unroll
      for (int jj = 0; jj < 4; ++jj)
#pragma unroll
        for (int r = 0; r < 4; ++r) {
          int sg = s0 + jj * 16 + quad * 4 + r;
          int i0 = sg - qg; i0 = i0 < -16 ? -16 : (i0 > 16 ? 16 : i0); i0 += 16;
          float e = __expf((c[jj][r] + pbrow[i0]) * 0.125f);
          lsum += e;
          pv[jj][r] = e;
        }
    }

    // packed P round-trip: 4x ds_write_b64 (bank-even swizzle), 2x b128 read
#pragma unroll
    for (int jj = 0; jj < 4; ++jj) {
      bf16x4 pw;
      pw[0] = (__bf16)pv[jj][0]; pw[1] = (__bf16)pv[jj][1];
      pw[2] = (__bf16)pv[jj][2]; pw[3] = (__bf16)pv[jj][3];
      int sl = (2 * jj + (quad >> 1)) ^ (l15 & 7);
      *(bf16x4*)&pbufw[(l15 << 6) + (sl << 3) + (quad & 1) * 4] = pw;
    }
    bf16x8 pa0 = *(const bf16x8*)&pbufw[SWZ(l15, quad)];
    bf16x8 pa1 = *(const bf16x8*)&pbufw[SWZ(l15, 4 + quad)];

    // PV: o[nt] += P(16q x 64s) @ V^T fragments
#pragma unroll
    for (int nt = 0; nt < 4; ++nt) {
      int vrow = nt * 16 + l15;
      bf16x8 vb0 = *(const bf16x8*)&Vs[SWZ(vrow, quad)];
      bf16x8 vb1 = *(const bf16x8*)&Vs[SWZ(vrow, 4 + quad)];
      o[nt] = __builtin_amdgcn_mfma_f32_16x16x32_bf16(pa0, vb0, o[nt], 0, 0, 0);
      o[nt] = __builtin_amdgcn_mfma_f32_16x16x32_bf16(pa1, vb1, o[nt], 0, 0, 0);
    }
  }

  // epilogue: lsum reduce across the 4 quads holding the same q, then
  // redistribute to the PV C-layout (q = quad*4 + r)
  lsum += __shfl_xor(lsum, 16, 64);
  lsum += __shfl_xor(lsum, 32, 64);
  float ls[4];
#pragma unroll
  for (int r = 0; r < 4; ++r) ls[r] = __shfl(lsum, quad * 4 + r, 64);
#pragma unroll
  for (int nt = 0; nt < 4; ++nt)
#pragma unroll
    for (int r = 0; r < 4; ++r) {
      int qq = qc + r;
      int d = nt * 16 + l15;
      ctx[(size_t)(b * S + qq) * DM + h * ADIM + d] =
          (__bf16)(o[nt][r] / ls[r]);
    }
}

extern "C" void kernel_launch(void* const* d_in, const int* in_sizes, int n_in,
                              void* d_out, int out_size, void* d_ws,
                              size_t ws_size, hipStream_t stream) {
  bool sizes_ok =
      (n_in == 8 && in_sizes[0] == BB * S * DM && in_sizes[1] == BB * S * DM &&
       in_sizes[2] == BB * S * DM && in_sizes[3] == DM * DM &&
       in_sizes[4] == DM * DM && in_sizes[5] == DM * DM &&
       in_sizes[6] == DM * DM && in_sizes[7] == NP * ADIM &&
       out_size == BB * S * DM);
  if (!sizes_ok) return;
  if (ws_size < 33ull * 1024 * 1024) return;

  const float* iQ = (const float*)d_in[0];
  const float* iK = (const float*)d_in[1];
  const float* iV = (const float*)d_in[2];
  const float* Wq = (const float*)d_in[3];
  const float* Wk = (const float*)d_in[4];
  const float* Wv = (const float*)d_in[5];
  const float* Wo = (const float*)d_in[6];
  const float* pemb = (const float*)d_in[7];

  char* w = (char*)d_ws;
  const size_t MB = 1024 * 1024;
  __bf16* Qw  = (__bf16*)(w + 0 * MB);
  __bf16* Kw  = (__bf16*)(w + 8 * MB);
  __bf16* Vt  = (__bf16*)(w + 16 * MB);  // [b,h,d,s]
  __bf16* ctx = (__bf16*)(w + 24 * MB);  // written by attn (24..32)
  __bf16* WqT = (__bf16*)(w + 24 * MB);  // overlay: dead before attn
  __bf16* WkT = (__bf16*)(w + 26 * MB);
  __bf16* WvT = (__bf16*)(w + 28 * MB);

  bool big = ws_size >= 58ull * 1024 * 1024;     // WoT @56MB, merged wtrans
  bool mid = ws_size >= 56ull * 1024 * 1024;     // bf16 prepass path
  __bf16* WoT = big ? (__bf16*)(w + 56 * MB) : (__bf16*)(w + 0 * MB);

  if (mid) {
    __bf16* Qb = (__bf16*)(w + 32 * MB);
    __bf16* Kb = (__bf16*)(w + 40 * MB);
    __bf16* Vb = (__bf16*)(w + 48 * MB);
    // transpose all 4 weights in one dispatch when WoT has a safe home
    wtrans<<<dim3(16, 16, big ? 4 : 3), 256, 0, stream>>>(
        Wq, Wk, Wv, Wo, WqT, WkT, WvT, WoT);
    tobf16<<<dim3(2048, 1, 3), 256, 0, stream>>>(iQ, iK, iV, Qb, Kb, Vb);
    proj3b<<<dim3(8, 32, 3), 256, 0, stream>>>(Qb, Kb, Vb, WqT, WkT, WvT,
                                               Qw, Kw, Vt);
    attn_flash<<<dim3(S / 64, BB * H), 256, 0, stream>>>(Qw, Kw, Vt, pemb,
                                                         ctx);
    if (!big)  // Qw slot only frees up after attn
      wtrans<<<dim3(16, 16, 1), 256, 0, stream>>>(Wo, Wo, Wo, Wo,
                                                  WoT, WoT, WoT, WoT);
  } else {
    wtrans<<<dim3(16, 16, 3), 256, 0, stream>>>(Wq, Wk, Wv, Wq,
                                                WqT, WkT, WvT, WqT);
    proj3<<<dim3(8, 32, 3), 256, 0, stream>>>(iQ, iK, iV, WqT, WkT, WvT,
                                              Qw, Kw, Vt);
    attn_flash<<<dim3(S / 64, BB * H), 256, 0, stream>>>(Qw, Kw, Vt, pemb,
                                                         ctx);
    wtrans<<<dim3(16, 16, 1), 256, 0, stream>>>(Wo, Wo, Wo, Wo,
                                                WoT, WoT, WoT, WoT);
  }
  gemm_final<<<dim3(16, 32), 256, 0, stream>>>(ctx, WoT, (float*)d_out);
}